// Round 1
// baseline (417.004 us; speedup 1.0000x reference)
//
#include <hip/hip_runtime.h>

typedef unsigned short u16;
typedef short bf16x8 __attribute__((ext_vector_type(8)));
typedef float f32x4 __attribute__((ext_vector_type(4)));
typedef unsigned short u16x4 __attribute__((ext_vector_type(4)));

#define AS1 __attribute__((address_space(1)))
#define AS3 __attribute__((address_space(3)))

__device__ __forceinline__ u16 f2bf(float f) {
    unsigned u = __float_as_uint(f);
    u += 0x7fff + ((u >> 16) & 1);   // round-to-nearest-even
    return (u16)(u >> 16);
}

__device__ __forceinline__ void gld16(const void* g, void* l) {
    __builtin_amdgcn_global_load_lds((const AS1 void*)g, (AS3 void*)l, 16, 0, 0);
}

// ---------------- fp32 -> bf16 conversion (vectorized) ----------------
__global__ void conv_bf16_kernel(const float* __restrict__ src, u16* __restrict__ dst, int n4) {
    int i = blockIdx.x * 256 + threadIdx.x;
    int stride = gridDim.x * 256;
    for (; i < n4; i += stride) {
        f32x4 v = ((const f32x4*)src)[i];
        u16x4 o = { f2bf(v.x), f2bf(v.y), f2bf(v.z), f2bf(v.w) };
        ((u16x4*)dst)[i] = o;
    }
}

// ---------------- cache_k: copy fp32 -> d_out K region + bf16 convert ----------------
__global__ void cachek_kernel(const float* __restrict__ ck, float* __restrict__ kout,
                              u16* __restrict__ kcb) {
    const int n4 = (2 * 16 * 1024 * 128) / 4;   // 1048576
    int i = blockIdx.x * 256 + threadIdx.x;
    int stride = gridDim.x * 256;
    for (; i < n4; i += stride) {
        f32x4 v = ((const f32x4*)ck)[i];
        int bh = i >> 15;                        // (i*4) >> 17
        ((f32x4*)kout)[i + bh * 32768] = v;      // [bh,s<1024,d] -> [bh*2048+s,d]
        u16x4 o = { f2bf(v.x), f2bf(v.y), f2bf(v.z), f2bf(v.w) };
        ((u16x4*)kcb)[i] = o;
    }
}

// ---------------- cache_v: copy fp32 -> d_out V region + bf16 transpose [bh,d,s] ----------------
__global__ void vtrans_kernel(const float* __restrict__ cv, float* __restrict__ vout,
                              u16* __restrict__ vtb) {
    __shared__ u16 tile[64 * 65];
    const int bh = blockIdx.x;
    const int s0 = blockIdx.y * 64;
    const int d0 = blockIdx.z * 64;
    const float* src = cv + (size_t)bh * 1024 * 128;
#pragma unroll
    for (int i = 0; i < 16; i++) {
        int e = i * 256 + threadIdx.x;
        int sr = e >> 6, dc = e & 63;
        float v = src[(size_t)(s0 + sr) * 128 + d0 + dc];
        vout[((size_t)bh * 2048 + s0 + sr) * 128 + d0 + dc] = v;
        tile[sr * 65 + dc] = f2bf(v);
    }
    __syncthreads();
    u16* dst = vtb + (size_t)bh * 128 * 1024;
#pragma unroll
    for (int i = 0; i < 16; i++) {
        int e = i * 256 + threadIdx.x;
        int dr = e >> 6, sc = e & 63;
        dst[(size_t)(d0 + dr) * 1024 + s0 + sc] = tile[sc * 65 + dr];
    }
}

// ---------------- bf16 GEMM: C[m,n] = sum_k A[m,k]*B[n,k], M=..., K=2048 ----------------
// MODE 0: QKV (N=6144 stacked): epilogue scatters Q (bf16, scaled), K/V (fp32 to cache slots)
// MODE 1: out-proj (N=2048): plain fp32 store
template <int MODE>
__global__ __launch_bounds__(256) void gemm_bt_kernel(
    const u16* __restrict__ A, const u16* __restrict__ Bm,
    u16* __restrict__ qout, float* __restrict__ kout, float* __restrict__ vout,
    float* __restrict__ cout) {
    __shared__ u16 As[128 * 32];
    __shared__ u16 Bs[128 * 32];
    const int tid = threadIdx.x;
    const int lane = tid & 63, wv = tid >> 6;
    const int wm = (wv >> 1) * 64, wn = (wv & 1) * 64;
    const int m0 = blockIdx.y * 128, n0 = blockIdx.x * 128;
    const int frow = lane & 15, fk = (lane >> 4) * 8;

    f32x4 acc[4][4];
#pragma unroll
    for (int a = 0; a < 4; a++)
#pragma unroll
        for (int b = 0; b < 4; b++) acc[a][b] = (f32x4){0.f, 0.f, 0.f, 0.f};

    for (int k0 = 0; k0 < 2048; k0 += 32) {
        __syncthreads();
#pragma unroll
        for (int i = 0; i < 2; i++) {
            int c = i * 256 + tid;
            int row = c >> 2, cc = c & 3;
            gld16(A + (size_t)(m0 + row) * 2048 + k0 + cc * 8, As + i * 2048 + wv * 512);
            gld16(Bm + (size_t)(n0 + row) * 2048 + k0 + cc * 8, Bs + i * 2048 + wv * 512);
        }
        __syncthreads();
        bf16x8 aF[4], bF[4];
#pragma unroll
        for (int f = 0; f < 4; f++) {
            aF[f] = *(const bf16x8*)(As + (wm + f * 16 + frow) * 32 + fk);
            bF[f] = *(const bf16x8*)(Bs + (wn + f * 16 + frow) * 32 + fk);
        }
#pragma unroll
        for (int fm = 0; fm < 4; fm++)
#pragma unroll
            for (int fn = 0; fn < 4; fn++)
                acc[fm][fn] = __builtin_amdgcn_mfma_f32_16x16x32_bf16(aF[fm], bF[fn], acc[fm][fn], 0, 0, 0);
    }

    const int q = lane >> 4, cl = lane & 15;
#pragma unroll
    for (int fm = 0; fm < 4; fm++) {
#pragma unroll
        for (int fn = 0; fn < 4; fn++) {
#pragma unroll
            for (int r = 0; r < 4; r++) {
                int m = m0 + wm + fm * 16 + q * 4 + r;
                int n = n0 + wn + fn * 16 + cl;
                float v = acc[fm][fn][r];
                if (MODE == 0) {
                    int b = m >> 10, t = m & 1023;
                    int sect = n >> 11, nn = n & 2047;
                    int h = nn >> 7, d = nn & 127;
                    size_t bh = (size_t)(b * 16 + h);
                    if (sect == 0)
                        qout[(bh * 1024 + t) * 128 + d] = f2bf(v * 0.08838834764831843f);
                    else if (sect == 1)
                        kout[(bh * 2048 + 1024 + t) * 128 + d] = v;
                    else
                        vout[(bh * 2048 + 1024 + t) * 128 + d] = v;
                } else {
                    cout[(size_t)m * 2048 + n] = v;
                }
            }
        }
    }
}

// ---------------- flash attention over cache: one block per (qtile=128, bh) ----------------
// Q pre-scaled by 1/sqrt(dk). s-tiles of 64, mask s<=t on the last two tiles.
__global__ __launch_bounds__(256) void attn_kernel(
    const u16* __restrict__ Qb, const u16* __restrict__ Kcb,
    const u16* __restrict__ Vtb, u16* __restrict__ AOb) {
    __shared__ u16 Qs[128 * 128];   // [t_local][d]
    __shared__ u16 Ks[64 * 128];    // [s_local][d]
    __shared__ u16 Vs[128 * 64];    // [d][s_local]  (transposed V)
    __shared__ u16 Ps[128 * 64];    // [t_local][s_local]
    const int qi = blockIdx.x, bh = blockIdx.y;
    const int t0 = qi * 128;
    const int tid = threadIdx.x, lane = tid & 63, wv = tid >> 6;
    const int wm = wv * 32;
    const int frow = lane & 15, fq = lane >> 4, fk = fq * 8;

    const u16* Qg = Qb + ((size_t)bh * 1024 + t0) * 128;
#pragma unroll
    for (int i = 0; i < 8; i++) {
        int ch = i * 256 + tid;
        int row = ch >> 4, cc = ch & 15;
        gld16(Qg + row * 128 + cc * 8, Qs + i * 2048 + wv * 512);
    }

    float mrow[2][4], lrow[2][4];
    f32x4 Oacc[2][8];
#pragma unroll
    for (int fm = 0; fm < 2; fm++) {
#pragma unroll
        for (int r = 0; r < 4; r++) { mrow[fm][r] = -1e30f; lrow[fm][r] = 0.f; }
#pragma unroll
        for (int fd = 0; fd < 8; fd++) Oacc[fm][fd] = (f32x4){0.f, 0.f, 0.f, 0.f};
    }

    const int nst = 2 * qi + 2;
    for (int st = 0; st < nst; st++) {
        int s0 = st * 64;
        __syncthreads();
        const u16* Kg = Kcb + ((size_t)bh * 1024 + s0) * 128;
#pragma unroll
        for (int i = 0; i < 4; i++) {
            int ch = i * 256 + tid;
            int row = ch >> 4, cc = ch & 15;
            gld16(Kg + row * 128 + cc * 8, Ks + i * 2048 + wv * 512);
        }
        const u16* Vg = Vtb + (size_t)bh * 131072 + s0;
#pragma unroll
        for (int i = 0; i < 4; i++) {
            int ch = i * 256 + tid;
            int dr = ch >> 3, cc = ch & 7;
            gld16(Vg + dr * 1024 + cc * 8, Vs + i * 2048 + wv * 512);
        }
        __syncthreads();

        // S = Q K^T  (Q pre-scaled)
        f32x4 S[2][4];
#pragma unroll
        for (int fm = 0; fm < 2; fm++)
#pragma unroll
            for (int fn = 0; fn < 4; fn++) S[fm][fn] = (f32x4){0.f, 0.f, 0.f, 0.f};
#pragma unroll
        for (int kk = 0; kk < 4; kk++) {
            bf16x8 aF[2], bF[4];
#pragma unroll
            for (int fm = 0; fm < 2; fm++)
                aF[fm] = *(const bf16x8*)(Qs + (wm + fm * 16 + frow) * 128 + kk * 32 + fk);
#pragma unroll
            for (int fn = 0; fn < 4; fn++)
                bF[fn] = *(const bf16x8*)(Ks + (fn * 16 + frow) * 128 + kk * 32 + fk);
#pragma unroll
            for (int fm = 0; fm < 2; fm++)
#pragma unroll
                for (int fn = 0; fn < 4; fn++)
                    S[fm][fn] = __builtin_amdgcn_mfma_f32_16x16x32_bf16(aF[fm], bF[fn], S[fm][fn], 0, 0, 0);
        }

        if (st >= 2 * qi) {   // diagonal tiles: mask s > t
#pragma unroll
            for (int fm = 0; fm < 2; fm++)
#pragma unroll
                for (int fn = 0; fn < 4; fn++)
#pragma unroll
                    for (int r = 0; r < 4; r++) {
                        int t = t0 + wm + fm * 16 + fq * 4 + r;
                        int s = s0 + fn * 16 + frow;
                        if (s > t) S[fm][fn][r] = -1e30f;
                    }
        }

        // online softmax per row
#pragma unroll
        for (int fm = 0; fm < 2; fm++) {
#pragma unroll
            for (int r = 0; r < 4; r++) {
                float mx = fmaxf(fmaxf(S[fm][0][r], S[fm][1][r]), fmaxf(S[fm][2][r], S[fm][3][r]));
                mx = fmaxf(mx, __shfl_xor(mx, 1));
                mx = fmaxf(mx, __shfl_xor(mx, 2));
                mx = fmaxf(mx, __shfl_xor(mx, 4));
                mx = fmaxf(mx, __shfl_xor(mx, 8));
                float mold = mrow[fm][r];
                float mnew = fmaxf(mold, mx);
                float alpha = __expf(mold - mnew);
                float rs = 0.f;
#pragma unroll
                for (int fn = 0; fn < 4; fn++) {
                    float p = __expf(S[fm][fn][r] - mnew);
                    S[fm][fn][r] = p;
                    rs += p;
                }
                rs += __shfl_xor(rs, 1);
                rs += __shfl_xor(rs, 2);
                rs += __shfl_xor(rs, 4);
                rs += __shfl_xor(rs, 8);
                mrow[fm][r] = mnew;
                lrow[fm][r] = lrow[fm][r] * alpha + rs;
#pragma unroll
                for (int fd = 0; fd < 8; fd++) Oacc[fm][fd][r] *= alpha;
            }
        }

        // P -> LDS (C-layout -> A-layout transform), per-wave region, no barrier needed
#pragma unroll
        for (int fm = 0; fm < 2; fm++)
#pragma unroll
            for (int fn = 0; fn < 4; fn++)
#pragma unroll
                for (int r = 0; r < 4; r++)
                    Ps[(wm + fm * 16 + fq * 4 + r) * 64 + fn * 16 + frow] = f2bf(S[fm][fn][r]);

        // O += P V
#pragma unroll
        for (int ks = 0; ks < 2; ks++) {
            bf16x8 aP[2], bV[8];
#pragma unroll
            for (int fm = 0; fm < 2; fm++)
                aP[fm] = *(const bf16x8*)(Ps + (wm + fm * 16 + frow) * 64 + ks * 32 + fk);
#pragma unroll
            for (int fd = 0; fd < 8; fd++)
                bV[fd] = *(const bf16x8*)(Vs + (fd * 16 + frow) * 64 + ks * 32 + fk);
#pragma unroll
            for (int fm = 0; fm < 2; fm++)
#pragma unroll
                for (int fd = 0; fd < 8; fd++)
                    Oacc[fm][fd] = __builtin_amdgcn_mfma_f32_16x16x32_bf16(aP[fm], bV[fd], Oacc[fm][fd], 0, 0, 0);
        }
    }

    // epilogue: merge heads -> AOb [b*1024+t, h*128+d] bf16
    const int b = bh >> 4, h = bh & 15;
#pragma unroll
    for (int fm = 0; fm < 2; fm++)
#pragma unroll
        for (int fd = 0; fd < 8; fd++)
#pragma unroll
            for (int r = 0; r < 4; r++) {
                int t = t0 + wm + fm * 16 + fq * 4 + r;
                int col = h * 128 + fd * 16 + frow;
                AOb[((size_t)b * 1024 + t) * 2048 + col] = f2bf(Oacc[fm][fd][r] / lrow[fm][r]);
            }
}

extern "C" void kernel_launch(void* const* d_in, const int* in_sizes, int n_in,
                              void* d_out, int out_size, void* d_ws, size_t ws_size,
                              hipStream_t stream) {
    const float* x  = (const float*)d_in[0];
    const float* ck = (const float*)d_in[1];
    const float* cv = (const float*)d_in[2];
    const float* Wq = (const float*)d_in[3];
    const float* Wk = (const float*)d_in[4];
    const float* Wv = (const float*)d_in[5];
    const float* Wo = (const float*)d_in[6];

    float* out  = (float*)d_out;               // [2048, 2048]
    float* Kout = out + 4194304;               // [B,H,2048,128]
    float* Vout = out + 12582912;              // [B,H,2048,128]

    u16* xb   = (u16*)d_ws;                    // [2048,2048]
    u16* Wqkv = xb + 4194304;                  // [6144,2048]
    u16* Wob  = Wqkv + 12582912;               // [2048,2048]
    u16* Qb   = Wob + 4194304;                 // [B,H,1024,128] (pre-scaled)
    u16* Kcb  = Qb + 4194304;                  // [B,H,1024,128]
    u16* Vtb  = Kcb + 4194304;                 // [B,H,128,1024]
    u16* AOb  = Vtb + 4194304;                 // [2048,2048]

    conv_bf16_kernel<<<1024, 256, 0, stream>>>(x, xb, 1048576);
    conv_bf16_kernel<<<1024, 256, 0, stream>>>(Wq, Wqkv, 1048576);
    conv_bf16_kernel<<<1024, 256, 0, stream>>>(Wk, Wqkv + 4194304, 1048576);
    conv_bf16_kernel<<<1024, 256, 0, stream>>>(Wv, Wqkv + 8388608, 1048576);
    conv_bf16_kernel<<<1024, 256, 0, stream>>>(Wo, Wob, 1048576);
    cachek_kernel<<<1024, 256, 0, stream>>>(ck, Kout, Kcb);
    vtrans_kernel<<<dim3(32, 16, 2), 256, 0, stream>>>(cv, Vout, Vtb);

    gemm_bt_kernel<0><<<dim3(48, 16), 256, 0, stream>>>(xb, Wqkv, Qb, Kout, Vout, nullptr);
    attn_kernel<<<dim3(8, 32), 256, 0, stream>>>(Qb, Kcb, Vtb, AOb);
    gemm_bt_kernel<1><<<dim3(16, 16), 256, 0, stream>>>(AOb, Wob, nullptr, nullptr, nullptr, out);
}

// Round 2
// 351.362 us; speedup vs baseline: 1.1868x; 1.1868x over previous
//
#include <hip/hip_runtime.h>

typedef unsigned short u16;
typedef short bf16x8 __attribute__((ext_vector_type(8)));
typedef float f32x4 __attribute__((ext_vector_type(4)));
typedef unsigned short u16x4 __attribute__((ext_vector_type(4)));

#define AS1 __attribute__((address_space(1)))
#define AS3 __attribute__((address_space(3)))

__device__ __forceinline__ u16 f2bf(float f) {
    unsigned u = __float_as_uint(f);
    u += 0x7fff + ((u >> 16) & 1);   // round-to-nearest-even
    return (u16)(u >> 16);
}

__device__ __forceinline__ void gld16(const void* g, void* l) {
    __builtin_amdgcn_global_load_lds((const AS1 void*)g, (AS3 void*)l, 16, 0, 0);
}

// ---------------- fused fp32 -> bf16 conversion for x, Wq, Wk, Wv, Wo ----------------
// grid 4096x256 = 2^20 threads; iteration r handles region r (wave-uniform).
__global__ void convall_kernel(const float* __restrict__ x,  const float* __restrict__ wq,
                               const float* __restrict__ wk, const float* __restrict__ wv,
                               const float* __restrict__ wo,
                               u16* __restrict__ xb, u16* __restrict__ wqkv, u16* __restrict__ wob) {
    int t = blockIdx.x * 256 + threadIdx.x;
    const float* srcs[5] = { x, wq, wk, wv, wo };
    u16* dsts[5] = { xb, wqkv, wqkv + 4194304, wqkv + 8388608, wob };
#pragma unroll
    for (int r = 0; r < 5; r++) {
        f32x4 v = ((const f32x4*)srcs[r])[t];
        u16x4 o = { f2bf(v.x), f2bf(v.y), f2bf(v.z), f2bf(v.w) };
        ((u16x4*)dsts[r])[t] = o;
    }
}

// ---------------- cache_k: copy fp32 -> d_out K region + bf16 convert ----------------
__global__ void cachek_kernel(const float* __restrict__ ck, float* __restrict__ kout,
                              u16* __restrict__ kcb) {
    const int n4 = (2 * 16 * 1024 * 128) / 4;   // 1048576
    int i = blockIdx.x * 256 + threadIdx.x;
    int stride = gridDim.x * 256;
    for (; i < n4; i += stride) {
        f32x4 v = ((const f32x4*)ck)[i];
        int bh = i >> 15;
        ((f32x4*)kout)[i + bh * 32768] = v;      // [bh,s<1024,d] -> [bh*2048+s,d]
        u16x4 o = { f2bf(v.x), f2bf(v.y), f2bf(v.z), f2bf(v.w) };
        ((u16x4*)kcb)[i] = o;
    }
}

// ---------------- cache_v: copy fp32 -> d_out V region + bf16 transpose [bh,d,s] ----------------
__global__ void vtrans_kernel(const float* __restrict__ cv, float* __restrict__ vout,
                              u16* __restrict__ vtb) {
    __shared__ u16 tile[64 * 65];
    const int bh = blockIdx.x;
    const int s0 = blockIdx.y * 64;
    const int d0 = blockIdx.z * 64;
    const float* src = cv + (size_t)bh * 1024 * 128;
#pragma unroll
    for (int i = 0; i < 16; i++) {
        int e = i * 256 + threadIdx.x;
        int sr = e >> 6, dc = e & 63;
        float v = src[(size_t)(s0 + sr) * 128 + d0 + dc];
        vout[((size_t)bh * 2048 + s0 + sr) * 128 + d0 + dc] = v;
        tile[sr * 65 + dc] = f2bf(v);
    }
    __syncthreads();
    u16* dst = vtb + (size_t)bh * 128 * 1024;
#pragma unroll
    for (int i = 0; i < 16; i++) {
        int e = i * 256 + threadIdx.x;
        int dr = e >> 6, sc = e & 63;
        dst[(size_t)(d0 + dr) * 1024 + s0 + sc] = tile[sc * 65 + dr];
    }
}

// ---------------- bf16 GEMM: C[m,n] = sum_k A[m,k]*B[n,k], K=2048, BK=64, XOR-swizzled LDS ----
// MODE 0: QKV (N=6144 stacked): epilogue scatters Q (bf16, scaled), K/V (fp32 to cache slots)
// MODE 1: out-proj (N=2048): plain fp32 store
template <int MODE>
__global__ __launch_bounds__(256) void gemm_bt_kernel(
    const u16* __restrict__ A, const u16* __restrict__ Bm,
    u16* __restrict__ qout, float* __restrict__ kout, float* __restrict__ vout,
    float* __restrict__ cout) {
    __shared__ u16 As[128 * 64];
    __shared__ u16 Bs[128 * 64];
    const int tid = threadIdx.x;
    const int lane = tid & 63, wv = tid >> 6;
    const int wm = (wv >> 1) * 64, wn = (wv & 1) * 64;
    const int m0 = blockIdx.y * 128, n0 = blockIdx.x * 128;
    const int frow = lane & 15, fq = lane >> 4;
    const int swz = frow & 7;

    f32x4 acc[4][4];
#pragma unroll
    for (int a = 0; a < 4; a++)
#pragma unroll
        for (int b = 0; b < 4; b++) acc[a][b] = (f32x4){0.f, 0.f, 0.f, 0.f};

    for (int k0 = 0; k0 < 2048; k0 += 64) {
        __syncthreads();
#pragma unroll
        for (int i = 0; i < 4; i++) {
            int L = i * 256 + tid;             // chunk index 0..1023 (8 elems each)
            int row = L >> 3;
            int c = (L & 7) ^ (row & 7);       // inverse swizzle -> global col chunk
            gld16(A + (size_t)(m0 + row) * 2048 + k0 + c * 8, As + i * 2048 + wv * 512);
            gld16(Bm + (size_t)(n0 + row) * 2048 + k0 + c * 8, Bs + i * 2048 + wv * 512);
        }
        __syncthreads();
#pragma unroll
        for (int kk = 0; kk < 2; kk++) {
            bf16x8 aF[4], bF[4];
#pragma unroll
            for (int f = 0; f < 4; f++) {
                aF[f] = *(const bf16x8*)(As + (wm + f * 16 + frow) * 64 + ((kk * 4 + fq) ^ swz) * 8);
                bF[f] = *(const bf16x8*)(Bs + (wn + f * 16 + frow) * 64 + ((kk * 4 + fq) ^ swz) * 8);
            }
#pragma unroll
            for (int fm = 0; fm < 4; fm++)
#pragma unroll
                for (int fn = 0; fn < 4; fn++)
                    acc[fm][fn] = __builtin_amdgcn_mfma_f32_16x16x32_bf16(aF[fm], bF[fn], acc[fm][fn], 0, 0, 0);
        }
    }

#pragma unroll
    for (int fm = 0; fm < 4; fm++) {
#pragma unroll
        for (int fn = 0; fn < 4; fn++) {
#pragma unroll
            for (int r = 0; r < 4; r++) {
                int m = m0 + wm + fm * 16 + fq * 4 + r;
                int n = n0 + wn + fn * 16 + frow;
                float v = acc[fm][fn][r];
                if (MODE == 0) {
                    int b = m >> 10, t = m & 1023;
                    int sect = n >> 11, nn = n & 2047;
                    int h = nn >> 7, d = nn & 127;
                    size_t bh = (size_t)(b * 16 + h);
                    if (sect == 0)
                        qout[(bh * 1024 + t) * 128 + d] = f2bf(v * 0.08838834764831843f);
                    else if (sect == 1)
                        kout[(bh * 2048 + 1024 + t) * 128 + d] = v;
                    else
                        vout[(bh * 2048 + 1024 + t) * 128 + d] = v;
                } else {
                    cout[(size_t)m * 2048 + n] = v;
                }
            }
        }
    }
}

// ---------------- flash attention: 64-row Q tiles, 64-col s tiles, swizzled LDS ----------------
// Grid: 512 blocks 1D; block i<256 -> (bh=i>>4, qi=i&15), i>=256 -> (bh=16+(j>>4), qi=15-(j&15))
// so blocks i and i+256 sum to a constant 17 s-tiles (balance under round-robin CU mapping).
__global__ __launch_bounds__(256) void attn_kernel(
    const u16* __restrict__ Qb, const u16* __restrict__ Kcb,
    const u16* __restrict__ Vtb, u16* __restrict__ AOb) {
    __shared__ u16 Qs[64 * 128];   // [t_local][d]  swizzled
    __shared__ u16 Ks[64 * 128];   // [s_local][d]  swizzled
    __shared__ u16 Vs[128 * 64];   // [d][s_local]  swizzled
    __shared__ u16 Ps[64 * 64];    // [t_local][s_local] swizzled
    int bid = blockIdx.x;
    int bh, qi;
    if (bid < 256) { bh = bid >> 4; qi = bid & 15; }
    else { int j = bid - 256; bh = 16 + (j >> 4); qi = 15 - (j & 15); }
    const int t0 = qi * 64;
    const int tid = threadIdx.x, lane = tid & 63, wv = tid >> 6;
    const int row_w = wv * 16;
    const int frow = lane & 15, fq = lane >> 4;
    const int swz = frow & 7;

    // stage Q (64x128 = 1024 chunks)
    const u16* Qg = Qb + ((size_t)bh * 1024 + t0) * 128;
#pragma unroll
    for (int i = 0; i < 4; i++) {
        int L = i * 256 + tid;
        int row = L >> 4;
        int c = (L & 15) ^ (row & 7);
        gld16(Qg + row * 128 + c * 8, Qs + i * 2048 + wv * 512);
    }

    float mrow[4], lrow[4];
    f32x4 Oacc[8];
#pragma unroll
    for (int r = 0; r < 4; r++) { mrow[r] = -1e30f; lrow[r] = 0.f; }
#pragma unroll
    for (int fd = 0; fd < 8; fd++) Oacc[fd] = (f32x4){0.f, 0.f, 0.f, 0.f};

    const int nst = qi + 1;
    for (int st = 0; st < nst; st++) {
        int s0 = st * 64;
        __syncthreads();
        const u16* Kg = Kcb + ((size_t)bh * 1024 + s0) * 128;
#pragma unroll
        for (int i = 0; i < 4; i++) {
            int L = i * 256 + tid;
            int row = L >> 4;
            int c = (L & 15) ^ (row & 7);
            gld16(Kg + row * 128 + c * 8, Ks + i * 2048 + wv * 512);
        }
        const u16* Vg = Vtb + (size_t)bh * 131072 + s0;
#pragma unroll
        for (int i = 0; i < 4; i++) {
            int L = i * 256 + tid;
            int row = L >> 3;
            int c = (L & 7) ^ (row & 7);
            gld16(Vg + row * 1024 + c * 8, Vs + i * 2048 + wv * 512);
        }
        __syncthreads();

        // S = Q K^T  (Q pre-scaled by 1/sqrt(dk))
        f32x4 S[4];
#pragma unroll
        for (int fn = 0; fn < 4; fn++) S[fn] = (f32x4){0.f, 0.f, 0.f, 0.f};
#pragma unroll
        for (int kk = 0; kk < 4; kk++) {
            bf16x8 aF = *(const bf16x8*)(Qs + (row_w + frow) * 128 + ((kk * 4 + fq) ^ swz) * 8);
#pragma unroll
            for (int fn = 0; fn < 4; fn++) {
                bf16x8 bF = *(const bf16x8*)(Ks + (fn * 16 + frow) * 128 + ((kk * 4 + fq) ^ swz) * 8);
                S[fn] = __builtin_amdgcn_mfma_f32_16x16x32_bf16(aF, bF, S[fn], 0, 0, 0);
            }
        }

        if (st == qi) {   // diagonal tile: mask s > t
#pragma unroll
            for (int fn = 0; fn < 4; fn++)
#pragma unroll
                for (int r = 0; r < 4; r++) {
                    int t = t0 + row_w + fq * 4 + r;
                    int s = s0 + fn * 16 + frow;
                    if (s > t) S[fn][r] = -1e30f;
                }
        }

        // online softmax per row
#pragma unroll
        for (int r = 0; r < 4; r++) {
            float mx = fmaxf(fmaxf(S[0][r], S[1][r]), fmaxf(S[2][r], S[3][r]));
            mx = fmaxf(mx, __shfl_xor(mx, 1));
            mx = fmaxf(mx, __shfl_xor(mx, 2));
            mx = fmaxf(mx, __shfl_xor(mx, 4));
            mx = fmaxf(mx, __shfl_xor(mx, 8));
            float mnew = fmaxf(mrow[r], mx);
            float alpha = __expf(mrow[r] - mnew);
            float rs = 0.f;
#pragma unroll
            for (int fn = 0; fn < 4; fn++) {
                float p = __expf(S[fn][r] - mnew);
                S[fn][r] = p;
                rs += p;
            }
            rs += __shfl_xor(rs, 1);
            rs += __shfl_xor(rs, 2);
            rs += __shfl_xor(rs, 4);
            rs += __shfl_xor(rs, 8);
            mrow[r] = mnew;
            lrow[r] = lrow[r] * alpha + rs;
#pragma unroll
            for (int fd = 0; fd < 8; fd++) Oacc[fd][r] *= alpha;
        }

        // P -> LDS (C-layout -> A-layout), per-wave region, swizzled; no barrier needed
#pragma unroll
        for (int fn = 0; fn < 4; fn++)
#pragma unroll
            for (int r = 0; r < 4; r++) {
                int pr = row_w + fq * 4 + r;
                int c = fn * 2 + (frow >> 3);
                Ps[pr * 64 + ((c ^ (pr & 7)) * 8) + (frow & 7)] = f2bf(S[fn][r]);
            }

        // O += P V
#pragma unroll
        for (int ks = 0; ks < 2; ks++) {
            int rr = row_w + frow;
            bf16x8 aP = *(const bf16x8*)(Ps + rr * 64 + ((ks * 4 + fq) ^ (rr & 7)) * 8);
#pragma unroll
            for (int fd = 0; fd < 8; fd++) {
                int vr = fd * 16 + frow;
                bf16x8 bV = *(const bf16x8*)(Vs + vr * 64 + ((ks * 4 + fq) ^ (vr & 7)) * 8);
                Oacc[fd] = __builtin_amdgcn_mfma_f32_16x16x32_bf16(aP, bV, Oacc[fd], 0, 0, 0);
            }
        }
    }

    // epilogue: merge heads -> AOb [b*1024+t, h*128+d] bf16
    const int b = bh >> 4, h = bh & 15;
#pragma unroll
    for (int r = 0; r < 4; r++) {
        float rl = 1.0f / lrow[r];
        int t = t0 + row_w + fq * 4 + r;
#pragma unroll
        for (int fd = 0; fd < 8; fd++) {
            int col = h * 128 + fd * 16 + frow;
            AOb[((size_t)b * 1024 + t) * 2048 + col] = f2bf(Oacc[fd][r] * rl);
        }
    }
}

extern "C" void kernel_launch(void* const* d_in, const int* in_sizes, int n_in,
                              void* d_out, int out_size, void* d_ws, size_t ws_size,
                              hipStream_t stream) {
    const float* x  = (const float*)d_in[0];
    const float* ck = (const float*)d_in[1];
    const float* cv = (const float*)d_in[2];
    const float* Wq = (const float*)d_in[3];
    const float* Wk = (const float*)d_in[4];
    const float* Wv = (const float*)d_in[5];
    const float* Wo = (const float*)d_in[6];

    float* out  = (float*)d_out;               // [2048, 2048]
    float* Kout = out + 4194304;               // [B,H,2048,128]
    float* Vout = out + 12582912;              // [B,H,2048,128]

    u16* xb   = (u16*)d_ws;                    // [2048,2048]
    u16* Wqkv = xb + 4194304;                  // [6144,2048]
    u16* Wob  = Wqkv + 12582912;               // [2048,2048]
    u16* Qb   = Wob + 4194304;                 // [B,H,1024,128] (pre-scaled)
    u16* Kcb  = Qb + 4194304;                  // [B,H,1024,128]
    u16* Vtb  = Kcb + 4194304;                 // [B,H,128,1024]
    u16* AOb  = Vtb + 4194304;                 // [2048,2048]

    convall_kernel<<<4096, 256, 0, stream>>>(x, Wq, Wk, Wv, Wo, xb, Wqkv, Wob);
    cachek_kernel<<<1024, 256, 0, stream>>>(ck, Kout, Kcb);
    vtrans_kernel<<<dim3(32, 16, 2), 256, 0, stream>>>(cv, Vout, Vtb);

    gemm_bt_kernel<0><<<dim3(48, 16), 256, 0, stream>>>(xb, Wqkv, Qb, Kout, Vout, nullptr);
    attn_kernel<<<512, 256, 0, stream>>>(Qb, Kcb, Vtb, AOb);
    gemm_bt_kernel<1><<<dim3(16, 16), 256, 0, stream>>>(AOb, Wob, nullptr, nullptr, nullptr, out);
}

// Round 3
// 351.226 us; speedup vs baseline: 1.1873x; 1.0004x over previous
//
#include <hip/hip_runtime.h>

typedef unsigned short u16;
typedef short bf16x8 __attribute__((ext_vector_type(8)));
typedef float f32x4 __attribute__((ext_vector_type(4)));
typedef unsigned short u16x4 __attribute__((ext_vector_type(4)));

#define AS1 __attribute__((address_space(1)))
#define AS3 __attribute__((address_space(3)))

__device__ __forceinline__ u16 f2bf(float f) {
    unsigned u = __float_as_uint(f);
    u += 0x7fff + ((u >> 16) & 1);   // round-to-nearest-even
    return (u16)(u >> 16);
}

__device__ __forceinline__ void gld16(const void* g, void* l) {
    __builtin_amdgcn_global_load_lds((const AS1 void*)g, (AS3 void*)l, 16, 0, 0);
}

// ---------------- fused fp32 -> bf16 conversion for x, Wq, Wk, Wv, Wo ----------------
__global__ void convall_kernel(const float* __restrict__ x,  const float* __restrict__ wq,
                               const float* __restrict__ wk, const float* __restrict__ wv,
                               const float* __restrict__ wo,
                               u16* __restrict__ xb, u16* __restrict__ wqkv, u16* __restrict__ wob) {
    int t = blockIdx.x * 256 + threadIdx.x;
    const float* srcs[5] = { x, wq, wk, wv, wo };
    u16* dsts[5] = { xb, wqkv, wqkv + 4194304, wqkv + 8388608, wob };
#pragma unroll
    for (int r = 0; r < 5; r++) {
        f32x4 v = ((const f32x4*)srcs[r])[t];
        u16x4 o = { f2bf(v.x), f2bf(v.y), f2bf(v.z), f2bf(v.w) };
        ((u16x4*)dsts[r])[t] = o;
    }
}

// ---------------- cache_k: copy fp32 -> d_out K region + bf16 convert ----------------
__global__ void cachek_kernel(const float* __restrict__ ck, float* __restrict__ kout,
                              u16* __restrict__ kcb) {
    const int n4 = (2 * 16 * 1024 * 128) / 4;   // 1048576
    int i = blockIdx.x * 256 + threadIdx.x;
    int stride = gridDim.x * 256;
    for (; i < n4; i += stride) {
        f32x4 v = ((const f32x4*)ck)[i];
        int bh = i >> 15;
        ((f32x4*)kout)[i + bh * 32768] = v;      // [bh,s<1024,d] -> [bh*2048+s,d]
        u16x4 o = { f2bf(v.x), f2bf(v.y), f2bf(v.z), f2bf(v.w) };
        ((u16x4*)kcb)[i] = o;
    }
}

// ---------------- cache_v: copy fp32 -> d_out V region + bf16 transpose [bh,d,s] ----------------
__global__ void vtrans_kernel(const float* __restrict__ cv, float* __restrict__ vout,
                              u16* __restrict__ vtb) {
    __shared__ u16 tile[64 * 65];
    const int bh = blockIdx.x;
    const int s0 = blockIdx.y * 64;
    const int d0 = blockIdx.z * 64;
    const float* src = cv + (size_t)bh * 1024 * 128;
#pragma unroll
    for (int i = 0; i < 16; i++) {
        int e = i * 256 + threadIdx.x;
        int sr = e >> 6, dc = e & 63;
        float v = src[(size_t)(s0 + sr) * 128 + d0 + dc];
        vout[((size_t)bh * 2048 + s0 + sr) * 128 + d0 + dc] = v;
        tile[sr * 65 + dc] = f2bf(v);
    }
    __syncthreads();
    u16* dst = vtb + (size_t)bh * 128 * 1024;
#pragma unroll
    for (int i = 0; i < 16; i++) {
        int e = i * 256 + threadIdx.x;
        int dr = e >> 6, sc = e & 63;
        dst[(size_t)(d0 + dr) * 1024 + s0 + sc] = tile[sc * 65 + dr];
    }
}

// ---------------- bf16 GEMM: C[m,n] = sum_k A[m,k]*B[n,k], K=2048 ----------------
// 64x64 tile, ONE wave per block, BK=64, XOR-swizzled LDS (16 KB -> ~10 blocks/CU).
// Single-wave blocks make the vmcnt drain private to the wave; ~10 independent
// resident waves/CU overlap each other's staging stalls.
// MODE 0: QKV (N=6144 stacked): epilogue scatters Q (bf16, scaled), K/V (fp32 to cache slots)
// MODE 1: out-proj (N=2048): plain fp32 store
template <int MODE>
__global__ __launch_bounds__(64, 3) void gemm_bt_kernel(
    const u16* __restrict__ A, const u16* __restrict__ Bm,
    u16* __restrict__ qout, float* __restrict__ kout, float* __restrict__ vout,
    float* __restrict__ cout) {
    __shared__ u16 As[64 * 64];
    __shared__ u16 Bs[64 * 64];
    const int lane = threadIdx.x;            // 64 threads = 1 wave
    const int m0 = blockIdx.y * 64, n0 = blockIdx.x * 64;
    const int frow = lane & 15, fq = lane >> 4;
    const int swz = frow & 7;

    f32x4 acc[4][4];
#pragma unroll
    for (int a = 0; a < 4; a++)
#pragma unroll
        for (int b = 0; b < 4; b++) acc[a][b] = (f32x4){0.f, 0.f, 0.f, 0.f};

    for (int k0 = 0; k0 < 2048; k0 += 64) {
        __syncthreads();
#pragma unroll
        for (int i = 0; i < 8; i++) {
            int L = i * 64 + lane;             // chunk index 0..511 (8 elems each)
            int row = L >> 3;
            int c = (L & 7) ^ (row & 7);       // inverse swizzle -> global col chunk
            gld16(A + (size_t)(m0 + row) * 2048 + k0 + c * 8, As + i * 512);
            gld16(Bm + (size_t)(n0 + row) * 2048 + k0 + c * 8, Bs + i * 512);
        }
        __syncthreads();
#pragma unroll
        for (int kk = 0; kk < 2; kk++) {
            bf16x8 aF[4], bF[4];
#pragma unroll
            for (int f = 0; f < 4; f++) {
                aF[f] = *(const bf16x8*)(As + (f * 16 + frow) * 64 + ((kk * 4 + fq) ^ swz) * 8);
                bF[f] = *(const bf16x8*)(Bs + (f * 16 + frow) * 64 + ((kk * 4 + fq) ^ swz) * 8);
            }
#pragma unroll
            for (int fm = 0; fm < 4; fm++)
#pragma unroll
                for (int fn = 0; fn < 4; fn++)
                    acc[fm][fn] = __builtin_amdgcn_mfma_f32_16x16x32_bf16(aF[fm], bF[fn], acc[fm][fn], 0, 0, 0);
        }
    }

#pragma unroll
    for (int fm = 0; fm < 4; fm++) {
#pragma unroll
        for (int fn = 0; fn < 4; fn++) {
#pragma unroll
            for (int r = 0; r < 4; r++) {
                int m = m0 + fm * 16 + fq * 4 + r;
                int n = n0 + fn * 16 + frow;
                float v = acc[fm][fn][r];
                if (MODE == 0) {
                    int b = m >> 10, t = m & 1023;
                    int sect = n >> 11, nn = n & 2047;
                    int h = nn >> 7, d = nn & 127;
                    size_t bh = (size_t)(b * 16 + h);
                    if (sect == 0)
                        qout[(bh * 1024 + t) * 128 + d] = f2bf(v * 0.08838834764831843f);
                    else if (sect == 1)
                        kout[(bh * 2048 + 1024 + t) * 128 + d] = v;
                    else
                        vout[(bh * 2048 + 1024 + t) * 128 + d] = v;
                } else {
                    cout[(size_t)m * 2048 + n] = v;
                }
            }
        }
    }
}

// ---------------- flash attention: 64-row Q tiles, 64-col s tiles, swizzled LDS ----------------
// Grid: 512 blocks 1D; block i<256 -> (bh=i>>4, qi=i&15), i>=256 -> (bh=16+(j>>4), qi=15-(j&15))
// so blocks i and i+256 sum to a constant 17 s-tiles (balance under round-robin CU mapping).
__global__ __launch_bounds__(256) void attn_kernel(
    const u16* __restrict__ Qb, const u16* __restrict__ Kcb,
    const u16* __restrict__ Vtb, u16* __restrict__ AOb) {
    __shared__ u16 Qs[64 * 128];   // [t_local][d]  swizzled
    __shared__ u16 Ks[64 * 128];   // [s_local][d]  swizzled
    __shared__ u16 Vs[128 * 64];   // [d][s_local]  swizzled
    __shared__ u16 Ps[64 * 64];    // [t_local][s_local] swizzled
    int bid = blockIdx.x;
    int bh, qi;
    if (bid < 256) { bh = bid >> 4; qi = bid & 15; }
    else { int j = bid - 256; bh = 16 + (j >> 4); qi = 15 - (j & 15); }
    const int t0 = qi * 64;
    const int tid = threadIdx.x, lane = tid & 63, wv = tid >> 6;
    const int row_w = wv * 16;
    const int frow = lane & 15, fq = lane >> 4;
    const int swz = frow & 7;

    // stage Q (64x128 = 1024 chunks)
    const u16* Qg = Qb + ((size_t)bh * 1024 + t0) * 128;
#pragma unroll
    for (int i = 0; i < 4; i++) {
        int L = i * 256 + tid;
        int row = L >> 4;
        int c = (L & 15) ^ (row & 7);
        gld16(Qg + row * 128 + c * 8, Qs + i * 2048 + wv * 512);
    }

    float mrow[4], lrow[4];
    f32x4 Oacc[8];
#pragma unroll
    for (int r = 0; r < 4; r++) { mrow[r] = -1e30f; lrow[r] = 0.f; }
#pragma unroll
    for (int fd = 0; fd < 8; fd++) Oacc[fd] = (f32x4){0.f, 0.f, 0.f, 0.f};

    const int nst = qi + 1;
    for (int st = 0; st < nst; st++) {
        int s0 = st * 64;
        __syncthreads();
        const u16* Kg = Kcb + ((size_t)bh * 1024 + s0) * 128;
#pragma unroll
        for (int i = 0; i < 4; i++) {
            int L = i * 256 + tid;
            int row = L >> 4;
            int c = (L & 15) ^ (row & 7);
            gld16(Kg + row * 128 + c * 8, Ks + i * 2048 + wv * 512);
        }
        const u16* Vg = Vtb + (size_t)bh * 131072 + s0;
#pragma unroll
        for (int i = 0; i < 4; i++) {
            int L = i * 256 + tid;
            int row = L >> 3;
            int c = (L & 7) ^ (row & 7);
            gld16(Vg + row * 1024 + c * 8, Vs + i * 2048 + wv * 512);
        }
        __syncthreads();

        // S = Q K^T  (Q pre-scaled by 1/sqrt(dk))
        f32x4 S[4];
#pragma unroll
        for (int fn = 0; fn < 4; fn++) S[fn] = (f32x4){0.f, 0.f, 0.f, 0.f};
#pragma unroll
        for (int kk = 0; kk < 4; kk++) {
            bf16x8 aF = *(const bf16x8*)(Qs + (row_w + frow) * 128 + ((kk * 4 + fq) ^ swz) * 8);
#pragma unroll
            for (int fn = 0; fn < 4; fn++) {
                bf16x8 bF = *(const bf16x8*)(Ks + (fn * 16 + frow) * 128 + ((kk * 4 + fq) ^ swz) * 8);
                S[fn] = __builtin_amdgcn_mfma_f32_16x16x32_bf16(aF, bF, S[fn], 0, 0, 0);
            }
        }

        if (st == qi) {   // diagonal tile: mask s > t
#pragma unroll
            for (int fn = 0; fn < 4; fn++)
#pragma unroll
                for (int r = 0; r < 4; r++) {
                    int t = t0 + row_w + fq * 4 + r;
                    int s = s0 + fn * 16 + frow;
                    if (s > t) S[fn][r] = -1e30f;
                }
        }

        // online softmax per row
#pragma unroll
        for (int r = 0; r < 4; r++) {
            float mx = fmaxf(fmaxf(S[0][r], S[1][r]), fmaxf(S[2][r], S[3][r]));
            mx = fmaxf(mx, __shfl_xor(mx, 1));
            mx = fmaxf(mx, __shfl_xor(mx, 2));
            mx = fmaxf(mx, __shfl_xor(mx, 4));
            mx = fmaxf(mx, __shfl_xor(mx, 8));
            float mnew = fmaxf(mrow[r], mx);
            float alpha = __expf(mrow[r] - mnew);
            float rs = 0.f;
#pragma unroll
            for (int fn = 0; fn < 4; fn++) {
                float p = __expf(S[fn][r] - mnew);
                S[fn][r] = p;
                rs += p;
            }
            rs += __shfl_xor(rs, 1);
            rs += __shfl_xor(rs, 2);
            rs += __shfl_xor(rs, 4);
            rs += __shfl_xor(rs, 8);
            mrow[r] = mnew;
            lrow[r] = lrow[r] * alpha + rs;
#pragma unroll
            for (int fd = 0; fd < 8; fd++) Oacc[fd][r] *= alpha;
        }

        // P -> LDS (C-layout -> A-layout), per-wave region, swizzled; no barrier needed
#pragma unroll
        for (int fn = 0; fn < 4; fn++)
#pragma unroll
            for (int r = 0; r < 4; r++) {
                int pr = row_w + fq * 4 + r;
                int c = fn * 2 + (frow >> 3);
                Ps[pr * 64 + ((c ^ (pr & 7)) * 8) + (frow & 7)] = f2bf(S[fn][r]);
            }

        // O += P V
#pragma unroll
        for (int ks = 0; ks < 2; ks++) {
            int rr = row_w + frow;
            bf16x8 aP = *(const bf16x8*)(Ps + rr * 64 + ((ks * 4 + fq) ^ (rr & 7)) * 8);
#pragma unroll
            for (int fd = 0; fd < 8; fd++) {
                int vr = fd * 16 + frow;
                bf16x8 bV = *(const bf16x8*)(Vs + vr * 64 + ((ks * 4 + fq) ^ (vr & 7)) * 8);
                Oacc[fd] = __builtin_amdgcn_mfma_f32_16x16x32_bf16(aP, bV, Oacc[fd], 0, 0, 0);
            }
        }
    }

    // epilogue: merge heads -> AOb [b*1024+t, h*128+d] bf16
    const int b = bh >> 4, h = bh & 15;
#pragma unroll
    for (int r = 0; r < 4; r++) {
        float rl = 1.0f / lrow[r];
        int t = t0 + row_w + fq * 4 + r;
#pragma unroll
        for (int fd = 0; fd < 8; fd++) {
            int col = h * 128 + fd * 16 + frow;
            AOb[((size_t)b * 1024 + t) * 2048 + col] = f2bf(Oacc[fd][r] * rl);
        }
    }
}

extern "C" void kernel_launch(void* const* d_in, const int* in_sizes, int n_in,
                              void* d_out, int out_size, void* d_ws, size_t ws_size,
                              hipStream_t stream) {
    const float* x  = (const float*)d_in[0];
    const float* ck = (const float*)d_in[1];
    const float* cv = (const float*)d_in[2];
    const float* Wq = (const float*)d_in[3];
    const float* Wk = (const float*)d_in[4];
    const float* Wv = (const float*)d_in[5];
    const float* Wo = (const float*)d_in[6];

    float* out  = (float*)d_out;               // [2048, 2048]
    float* Kout = out + 4194304;               // [B,H,2048,128]
    float* Vout = out + 12582912;              // [B,H,2048,128]

    u16* xb   = (u16*)d_ws;                    // [2048,2048]
    u16* Wqkv = xb + 4194304;                  // [6144,2048]
    u16* Wob  = Wqkv + 12582912;               // [2048,2048]
    u16* Qb   = Wob + 4194304;                 // [B,H,1024,128] (pre-scaled)
    u16* Kcb  = Qb + 4194304;                  // [B,H,1024,128]
    u16* Vtb  = Kcb + 4194304;                 // [B,H,128,1024]
    u16* AOb  = Vtb + 4194304;                 // [2048,2048]

    convall_kernel<<<4096, 256, 0, stream>>>(x, Wq, Wk, Wv, Wo, xb, Wqkv, Wob);
    cachek_kernel<<<1024, 256, 0, stream>>>(ck, Kout, Kcb);
    vtrans_kernel<<<dim3(32, 16, 2), 256, 0, stream>>>(cv, Vout, Vtb);

    gemm_bt_kernel<0><<<dim3(96, 32), 64, 0, stream>>>(xb, Wqkv, Qb, Kout, Vout, nullptr);
    attn_kernel<<<512, 256, 0, stream>>>(Qb, Kcb, Vtb, AOb);
    gemm_bt_kernel<1><<<dim3(32, 32), 64, 0, stream>>>(AOb, Wob, nullptr, nullptr, nullptr, out);
}

// Round 4
// 324.815 us; speedup vs baseline: 1.2838x; 1.0813x over previous
//
#include <hip/hip_runtime.h>

typedef unsigned short u16;
typedef short bf16x8 __attribute__((ext_vector_type(8)));
typedef float f32x4 __attribute__((ext_vector_type(4)));
typedef unsigned short u16x4 __attribute__((ext_vector_type(4)));

#define AS1 __attribute__((address_space(1)))
#define AS3 __attribute__((address_space(3)))

__device__ __forceinline__ u16 f2bf(float f) {
    unsigned u = __float_as_uint(f);
    u += 0x7fff + ((u >> 16) & 1);   // round-to-nearest-even
    return (u16)(u >> 16);
}

__device__ __forceinline__ void gld16(const void* g, void* l) {
    __builtin_amdgcn_global_load_lds((const AS1 void*)g, (AS3 void*)l, 16, 0, 0);
}

// ---------------- fused fp32 -> bf16 conversion for x, Wq, Wk, Wv, Wo ----------------
__global__ void convall_kernel(const float* __restrict__ x,  const float* __restrict__ wq,
                               const float* __restrict__ wk, const float* __restrict__ wv,
                               const float* __restrict__ wo,
                               u16* __restrict__ xb, u16* __restrict__ wqkv, u16* __restrict__ wob) {
    int t = blockIdx.x * 256 + threadIdx.x;
    const float* srcs[5] = { x, wq, wk, wv, wo };
    u16* dsts[5] = { xb, wqkv, wqkv + 4194304, wqkv + 8388608, wob };
#pragma unroll
    for (int r = 0; r < 5; r++) {
        f32x4 v = ((const f32x4*)srcs[r])[t];
        u16x4 o = { f2bf(v.x), f2bf(v.y), f2bf(v.z), f2bf(v.w) };
        ((u16x4*)dsts[r])[t] = o;
    }
}

// ---------------- cache_k: copy fp32 -> d_out K region + bf16 convert ----------------
__global__ void cachek_kernel(const float* __restrict__ ck, float* __restrict__ kout,
                              u16* __restrict__ kcb) {
    const int n4 = (2 * 16 * 1024 * 128) / 4;   // 1048576
    int i = blockIdx.x * 256 + threadIdx.x;
    int stride = gridDim.x * 256;
    for (; i < n4; i += stride) {
        f32x4 v = ((const f32x4*)ck)[i];
        int bh = i >> 15;
        ((f32x4*)kout)[i + bh * 32768] = v;      // [bh,s<1024,d] -> [bh*2048+s,d]
        u16x4 o = { f2bf(v.x), f2bf(v.y), f2bf(v.z), f2bf(v.w) };
        ((u16x4*)kcb)[i] = o;
    }
}

// ---------------- cache_v: copy fp32 -> d_out V region + bf16 transpose [bh,d,s] ----------------
__global__ void vtrans_kernel(const float* __restrict__ cv, float* __restrict__ vout,
                              u16* __restrict__ vtb) {
    __shared__ u16 tile[64 * 65];
    const int bh = blockIdx.x;
    const int s0 = blockIdx.y * 64;
    const int d0 = blockIdx.z * 64;
    const float* src = cv + (size_t)bh * 1024 * 128;
#pragma unroll
    for (int i = 0; i < 16; i++) {
        int e = i * 256 + threadIdx.x;
        int sr = e >> 6, dc = e & 63;
        float v = src[(size_t)(s0 + sr) * 128 + d0 + dc];
        vout[((size_t)bh * 2048 + s0 + sr) * 128 + d0 + dc] = v;
        tile[sr * 65 + dc] = f2bf(v);
    }
    __syncthreads();
    u16* dst = vtb + (size_t)bh * 128 * 1024;
#pragma unroll
    for (int i = 0; i < 16; i++) {
        int e = i * 256 + threadIdx.x;
        int dr = e >> 6, sc = e & 63;
        dst[(size_t)(d0 + dr) * 1024 + s0 + sc] = tile[sc * 65 + dr];
    }
}

// ---------------- bf16 GEMM: C[m,n] = sum_k A[m,k]*B[n,k], K=2048 ----------------
// 64x128 tile, 4 waves (each 64x32), BK=64, XOR-swizzled LDS (24 KB -> 5-6 blocks/CU).
// B-tile staging shared by all 4 waves; block count 2x vs 128x128 tiling.
// MODE 0: QKV (N=6144 stacked): epilogue scatters Q (bf16, scaled), K/V (fp32 to cache slots)
// MODE 1: out-proj (N=2048): plain fp32 store
template <int MODE>
__global__ __launch_bounds__(256) void gemm_bt_kernel(
    const u16* __restrict__ A, const u16* __restrict__ Bm,
    u16* __restrict__ qout, float* __restrict__ kout, float* __restrict__ vout,
    float* __restrict__ cout) {
    __shared__ u16 As[64 * 64];     // 8 KB
    __shared__ u16 Bs[128 * 64];    // 16 KB
    const int tid = threadIdx.x;
    const int lane = tid & 63, wv = tid >> 6;
    const int wn = wv * 32;
    const int m0 = blockIdx.y * 64, n0 = blockIdx.x * 128;
    const int frow = lane & 15, fq = lane >> 4;
    const int swz = frow & 7;

    f32x4 acc[4][2];
#pragma unroll
    for (int a = 0; a < 4; a++)
#pragma unroll
        for (int b = 0; b < 2; b++) acc[a][b] = (f32x4){0.f, 0.f, 0.f, 0.f};

    for (int k0 = 0; k0 < 2048; k0 += 64) {
        __syncthreads();
#pragma unroll
        for (int i = 0; i < 2; i++) {
            int L = i * 256 + tid;             // A chunk 0..511
            int row = L >> 3;
            int c = (L & 7) ^ (row & 7);
            gld16(A + (size_t)(m0 + row) * 2048 + k0 + c * 8, As + i * 2048 + wv * 512);
        }
#pragma unroll
        for (int i = 0; i < 4; i++) {
            int L = i * 256 + tid;             // B chunk 0..1023
            int row = L >> 3;
            int c = (L & 7) ^ (row & 7);
            gld16(Bm + (size_t)(n0 + row) * 2048 + k0 + c * 8, Bs + i * 2048 + wv * 512);
        }
        __syncthreads();
#pragma unroll
        for (int kk = 0; kk < 2; kk++) {
            bf16x8 aF[4], bF[2];
#pragma unroll
            for (int f = 0; f < 4; f++)
                aF[f] = *(const bf16x8*)(As + (f * 16 + frow) * 64 + ((kk * 4 + fq) ^ swz) * 8);
#pragma unroll
            for (int f = 0; f < 2; f++)
                bF[f] = *(const bf16x8*)(Bs + (wn + f * 16 + frow) * 64 + ((kk * 4 + fq) ^ swz) * 8);
#pragma unroll
            for (int fm = 0; fm < 4; fm++)
#pragma unroll
                for (int fn = 0; fn < 2; fn++)
                    acc[fm][fn] = __builtin_amdgcn_mfma_f32_16x16x32_bf16(aF[fm], bF[fn], acc[fm][fn], 0, 0, 0);
        }
    }

#pragma unroll
    for (int fm = 0; fm < 4; fm++) {
#pragma unroll
        for (int fn = 0; fn < 2; fn++) {
#pragma unroll
            for (int r = 0; r < 4; r++) {
                int m = m0 + fm * 16 + fq * 4 + r;
                int n = n0 + wn + fn * 16 + frow;
                float v = acc[fm][fn][r];
                if (MODE == 0) {
                    int b = m >> 10, t = m & 1023;
                    int sect = n >> 11, nn = n & 2047;
                    int h = nn >> 7, d = nn & 127;
                    size_t bh = (size_t)(b * 16 + h);
                    if (sect == 0)
                        qout[(bh * 1024 + t) * 128 + d] = f2bf(v * 0.08838834764831843f);
                    else if (sect == 1)
                        kout[(bh * 2048 + 1024 + t) * 128 + d] = v;
                    else
                        vout[(bh * 2048 + 1024 + t) * 128 + d] = v;
                } else {
                    cout[(size_t)m * 2048 + n] = v;
                }
            }
        }
    }
}

// ---------------- flash attention, s-split for load balance ----------------
// 768 blocks, heavy-first:
//  bid<512: partial chunks of qi in [8,15]: qi = 15-(bid>>6), bh=(bid&63)>>1, c=bid&1.
//           chunk0 = tiles [0,ceil(n/2)), chunk1 = rest (incl. diagonal). Writes raw
//           m/l/O partials to workspace (overlaid on dead Wqkv region).
//  bid>=512: full blocks qi in [0,7] (loads 1..8), qi = 7-((bid-512)>>5), bh=(bid-512)&31.
// All block loads in [1..8.5] tiles; 768 blocks on 512 slots -> LPT-style balance.
__global__ __launch_bounds__(256) void attn_kernel(
    const u16* __restrict__ Qb, const u16* __restrict__ Kcb,
    const u16* __restrict__ Vtb, u16* __restrict__ AOb,
    float* __restrict__ PO, float* __restrict__ PML) {
    __shared__ u16 Qs[64 * 128];   // [t_local][d]  swizzled
    __shared__ u16 Ks[64 * 128];   // [s_local][d]  swizzled
    __shared__ u16 Vs[128 * 64];   // [d][s_local]  swizzled
    __shared__ u16 Ps[64 * 64];    // [t_local][s_local] swizzled
    const int bid = blockIdx.x;
    int bh, qi, st_begin, st_end, cidx;
    bool partial;
    if (bid < 512) {
        qi = 15 - (bid >> 6);
        int j = bid & 63;
        bh = j >> 1;
        int c = j & 1;
        int n = qi + 1, h0 = (n + 1) >> 1;
        st_begin = c ? h0 : 0;
        st_end = c ? n : h0;
        partial = true;
        cidx = c * 256 + bh * 8 + (qi - 8);
    } else {
        int j = bid - 512;
        qi = 7 - (j >> 5);
        bh = j & 31;
        st_begin = 0; st_end = qi + 1;
        partial = false; cidx = 0;
    }
    const int t0 = qi * 64;
    const int tid = threadIdx.x, lane = tid & 63, wv = tid >> 6;
    const int row_w = wv * 16;
    const int frow = lane & 15, fq = lane >> 4;
    const int swz = frow & 7;

    // stage Q (64x128 = 1024 chunks)
    const u16* Qg = Qb + ((size_t)bh * 1024 + t0) * 128;
#pragma unroll
    for (int i = 0; i < 4; i++) {
        int L = i * 256 + tid;
        int row = L >> 4;
        int c = (L & 15) ^ (row & 7);
        gld16(Qg + row * 128 + c * 8, Qs + i * 2048 + wv * 512);
    }

    float mrow[4], lrow[4];
    f32x4 Oacc[8];
#pragma unroll
    for (int r = 0; r < 4; r++) { mrow[r] = -1e30f; lrow[r] = 0.f; }
#pragma unroll
    for (int fd = 0; fd < 8; fd++) Oacc[fd] = (f32x4){0.f, 0.f, 0.f, 0.f};

    for (int st = st_begin; st < st_end; st++) {
        int s0 = st * 64;
        __syncthreads();
        const u16* Kg = Kcb + ((size_t)bh * 1024 + s0) * 128;
#pragma unroll
        for (int i = 0; i < 4; i++) {
            int L = i * 256 + tid;
            int row = L >> 4;
            int c = (L & 15) ^ (row & 7);
            gld16(Kg + row * 128 + c * 8, Ks + i * 2048 + wv * 512);
        }
        const u16* Vg = Vtb + (size_t)bh * 131072 + s0;
#pragma unroll
        for (int i = 0; i < 4; i++) {
            int L = i * 256 + tid;
            int row = L >> 3;
            int c = (L & 7) ^ (row & 7);
            gld16(Vg + row * 1024 + c * 8, Vs + i * 2048 + wv * 512);
        }
        __syncthreads();

        // S = Q K^T  (Q pre-scaled by 1/sqrt(dk))
        f32x4 S[4];
#pragma unroll
        for (int fn = 0; fn < 4; fn++) S[fn] = (f32x4){0.f, 0.f, 0.f, 0.f};
#pragma unroll
        for (int kk = 0; kk < 4; kk++) {
            bf16x8 aF = *(const bf16x8*)(Qs + (row_w + frow) * 128 + ((kk * 4 + fq) ^ swz) * 8);
#pragma unroll
            for (int fn = 0; fn < 4; fn++) {
                bf16x8 bF = *(const bf16x8*)(Ks + (fn * 16 + frow) * 128 + ((kk * 4 + fq) ^ swz) * 8);
                S[fn] = __builtin_amdgcn_mfma_f32_16x16x32_bf16(aF, bF, S[fn], 0, 0, 0);
            }
        }

        if (st == qi) {   // diagonal tile: mask s > t
#pragma unroll
            for (int fn = 0; fn < 4; fn++)
#pragma unroll
                for (int r = 0; r < 4; r++) {
                    int t = t0 + row_w + fq * 4 + r;
                    int s = s0 + fn * 16 + frow;
                    if (s > t) S[fn][r] = -1e30f;
                }
        }

        // online softmax per row
#pragma unroll
        for (int r = 0; r < 4; r++) {
            float mx = fmaxf(fmaxf(S[0][r], S[1][r]), fmaxf(S[2][r], S[3][r]));
            mx = fmaxf(mx, __shfl_xor(mx, 1));
            mx = fmaxf(mx, __shfl_xor(mx, 2));
            mx = fmaxf(mx, __shfl_xor(mx, 4));
            mx = fmaxf(mx, __shfl_xor(mx, 8));
            float mnew = fmaxf(mrow[r], mx);
            float alpha = __expf(mrow[r] - mnew);
            float rs = 0.f;
#pragma unroll
            for (int fn = 0; fn < 4; fn++) {
                float p = __expf(S[fn][r] - mnew);
                S[fn][r] = p;
                rs += p;
            }
            rs += __shfl_xor(rs, 1);
            rs += __shfl_xor(rs, 2);
            rs += __shfl_xor(rs, 4);
            rs += __shfl_xor(rs, 8);
            mrow[r] = mnew;
            lrow[r] = lrow[r] * alpha + rs;
#pragma unroll
            for (int fd = 0; fd < 8; fd++) Oacc[fd][r] *= alpha;
        }

        // P -> LDS (C-layout -> A-layout), per-wave region, swizzled; no barrier needed
#pragma unroll
        for (int fn = 0; fn < 4; fn++)
#pragma unroll
            for (int r = 0; r < 4; r++) {
                int pr = row_w + fq * 4 + r;
                int c = fn * 2 + (frow >> 3);
                Ps[pr * 64 + ((c ^ (pr & 7)) * 8) + (frow & 7)] = f2bf(S[fn][r]);
            }

        // O += P V
#pragma unroll
        for (int ks = 0; ks < 2; ks++) {
            int rr = row_w + frow;
            bf16x8 aP = *(const bf16x8*)(Ps + rr * 64 + ((ks * 4 + fq) ^ (rr & 7)) * 8);
#pragma unroll
            for (int fd = 0; fd < 8; fd++) {
                int vr = fd * 16 + frow;
                bf16x8 bV = *(const bf16x8*)(Vs + vr * 64 + ((ks * 4 + fq) ^ (vr & 7)) * 8);
                Oacc[fd] = __builtin_amdgcn_mfma_f32_16x16x32_bf16(aP, bV, Oacc[fd], 0, 0, 0);
            }
        }
    }

    if (partial) {
        // raw partial: O (un-normalized), m, l
        float* Od = PO + (size_t)cidx * 8192;
#pragma unroll
        for (int r = 0; r < 4; r++) {
            int row = row_w + fq * 4 + r;
#pragma unroll
            for (int fd = 0; fd < 8; fd++)
                Od[row * 128 + fd * 16 + frow] = Oacc[fd][r];
        }
        if (frow == 0) {
#pragma unroll
            for (int r = 0; r < 4; r++) {
                int row = row_w + fq * 4 + r;
                PML[cidx * 128 + row * 2] = mrow[r];
                PML[cidx * 128 + row * 2 + 1] = lrow[r];
            }
        }
    } else {
        // final: merge heads -> AOb [b*1024+t, h*128+d] bf16
        const int b = bh >> 4, h = bh & 15;
#pragma unroll
        for (int r = 0; r < 4; r++) {
            float rl = 1.0f / lrow[r];
            int t = t0 + row_w + fq * 4 + r;
#pragma unroll
            for (int fd = 0; fd < 8; fd++) {
                int col = h * 128 + fd * 16 + frow;
                AOb[((size_t)b * 1024 + t) * 2048 + col] = f2bf(Oacc[fd][r] * rl);
            }
        }
    }
}

// ---------------- merge the two s-chunks for qi >= 8 ----------------
__global__ __launch_bounds__(256) void attn_merge_kernel(
    const float* __restrict__ PO, const float* __restrict__ PML, u16* __restrict__ AOb) {
    const int idx = blockIdx.x;                // 0..255
    const int bh = idx >> 3, qi = 8 + (idx & 7);
    const int t0 = qi * 64;
    const int b = bh >> 4, h = bh & 15;
    const int tid = threadIdx.x;
    const int row = tid >> 2, cg = tid & 3;    // 64 rows x 4 col-groups of 32
    const float* O0 = PO + (size_t)idx * 8192;
    const float* O1 = PO + (size_t)(256 + idx) * 8192;
    float m0 = PML[idx * 128 + row * 2],        l0 = PML[idx * 128 + row * 2 + 1];
    float m1 = PML[(256 + idx) * 128 + row * 2], l1 = PML[(256 + idx) * 128 + row * 2 + 1];
    float mm = fmaxf(m0, m1);
    float w0 = __expf(m0 - mm), w1 = __expf(m1 - mm);
    float inv = 1.0f / (l0 * w0 + l1 * w1);
    u16* dst = AOb + ((size_t)b * 1024 + t0 + row) * 2048 + h * 128 + cg * 32;
#pragma unroll
    for (int j = 0; j < 8; j++) {
        f32x4 a = *(const f32x4*)(O0 + row * 128 + cg * 32 + j * 4);
        f32x4 c = *(const f32x4*)(O1 + row * 128 + cg * 32 + j * 4);
        u16x4 o = { f2bf((a.x * w0 + c.x * w1) * inv), f2bf((a.y * w0 + c.y * w1) * inv),
                    f2bf((a.z * w0 + c.z * w1) * inv), f2bf((a.w * w0 + c.w * w1) * inv) };
        *(u16x4*)(dst + j * 4) = o;
    }
}

extern "C" void kernel_launch(void* const* d_in, const int* in_sizes, int n_in,
                              void* d_out, int out_size, void* d_ws, size_t ws_size,
                              hipStream_t stream) {
    const float* x  = (const float*)d_in[0];
    const float* ck = (const float*)d_in[1];
    const float* cv = (const float*)d_in[2];
    const float* Wq = (const float*)d_in[3];
    const float* Wk = (const float*)d_in[4];
    const float* Wv = (const float*)d_in[5];
    const float* Wo = (const float*)d_in[6];

    float* out  = (float*)d_out;               // [2048, 2048]
    float* Kout = out + 4194304;               // [B,H,2048,128]
    float* Vout = out + 12582912;              // [B,H,2048,128]

    u16* xb   = (u16*)d_ws;                    // [2048,2048]
    u16* Wqkv = xb + 4194304;                  // [6144,2048] (dead after gemm0)
    u16* Wob  = Wqkv + 12582912;               // [2048,2048]
    u16* Qb   = Wob + 4194304;                 // [B,H,1024,128] (pre-scaled)
    u16* Kcb  = Qb + 4194304;                  // [B,H,1024,128]
    u16* Vtb  = Kcb + 4194304;                 // [B,H,128,1024]
    u16* AOb  = Vtb + 4194304;                 // [2048,2048]
    // attention partials overlaid on dead Wqkv region (25.1 MB; we use 17 MB)
    float* PO  = (float*)Wqkv;                 // 2*256*8192 floats
    float* PML = PO + 4194304;                 // 2*256*128 floats

    convall_kernel<<<4096, 256, 0, stream>>>(x, Wq, Wk, Wv, Wo, xb, Wqkv, Wob);
    cachek_kernel<<<1024, 256, 0, stream>>>(ck, Kout, Kcb);
    vtrans_kernel<<<dim3(32, 16, 2), 256, 0, stream>>>(cv, Vout, Vtb);

    gemm_bt_kernel<0><<<dim3(48, 32), 256, 0, stream>>>(xb, Wqkv, Qb, Kout, Vout, nullptr);
    attn_kernel<<<768, 256, 0, stream>>>(Qb, Kcb, Vtb, AOb, PO, PML);
    attn_merge_kernel<<<256, 256, 0, stream>>>(PO, PML, AOb);
    gemm_bt_kernel<1><<<dim3(16, 32), 256, 0, stream>>>(AOb, Wob, nullptr, nullptr, nullptr, out);
}